// Round 6
// baseline (225.031 us; speedup 1.0000x reference)
//
#include <hip/hip_runtime.h>
#include <hip/hip_bf16.h>

// Problem constants (fixed by setup_inputs):
//   n = 4096, dc = 4096, nb = 4, db = 2048, T buckets = 5000
#define N_SAMP 4096
#define DC     4096
#define NB     4
#define DB     2048
#define TBKT   5000

#define CVEC (N_SAMP * DC / 4)   // 4,194,304 vec4 in common region
#define BVEC (N_SAMP * DB / 4)   // 2,097,152 vec4 per block region
#define TILE 4096                // vec4 per tile (region-pure)
#define NWSE ((CVEC + NB * BVEC) / TILE)  // 3072 wse tiles
#define NCOX 5

typedef float vf4 __attribute__((ext_vector_type(4)));  // builtin-compatible

__device__ inline float ssq(const vf4& x, const vf4& y) {
    float d0 = x.x - y.x, d1 = x.y - y.y, d2 = x.z - y.z, d3 = x.w - y.w;
    return d0 * d0 + d1 * d1 + d2 * d2 + d3 * d3;
}

__device__ inline float block_reduce_sum(float v, volatile float* sm) {
    #pragma unroll
    for (int off = 32; off > 0; off >>= 1) v += __shfl_down(v, off);
    int lane = threadIdx.x & 63;
    int wid  = threadIdx.x >> 6;
    if (lane == 0) sm[wid] = v;
    __syncthreads();
    float r = 0.f;
    if (wid == 0) {
        r = (lane < 4) ? sm[lane] : 0.f;
        r += __shfl_down(r, 2);
        r += __shfl_down(r, 1);
    }
    return r;  // valid on thread 0
}

// Single fused kernel. Blocks [0,NCOX): the 5 Cox losses (dispatch first,
// overlap with the wse flood). Blocks [NCOX, NCOX+NWSE): weighted-squared-
// error streaming reduction. ws[0..4]=region sums, ws[5]=completion counter;
// the last wse block to finish also produces out[1..5] (no finalize launch).
__global__ __launch_bounds__(256) void fused_kernel(
    const float* __restrict__ pred,
    const float* __restrict__ ct, const float* __restrict__ cr,
    const float* __restrict__ bt, const float* __restrict__ br,
    const float* __restrict__ bh,
    const float* __restrict__ sw, const int* __restrict__ st,
    const int* __restrict__ se,
    float* __restrict__ ws, float* __restrict__ out)
{
    __shared__ float hist[TBKT];
    __shared__ float scan[256];
    __shared__ float smr[8];
    const int tid = threadIdx.x;

    if (blockIdx.x >= NCOX) {
        const int tile = blockIdx.x - NCOX;
        const vf4* a;
        const vf4* b;
        int region, rowShift, vloc;
        if (tile < CVEC / TILE) {
            region = 0; rowShift = 10;       // 1024 vec4 per row
            a = (const vf4*)ct; b = (const vf4*)cr;
            vloc = tile * TILE;
        } else {
            const int q   = tile - CVEC / TILE;
            const int blk = q >> 9;          // 512 tiles per block region
            region = 1 + blk; rowShift = 9;  // 512 vec4 per row
            a = (const vf4*)bt + (size_t)blk * BVEC;
            b = (const vf4*)br + (size_t)blk * BVEC;
            vloc = (q & 511) * TILE;
        }
        const int v0 = vloc + tid;

        float acc = 0.f;
        #pragma unroll
        for (int outer = 0; outer < 2; ++outer) {
            vf4 xa[8], ya[8];
            float wv[8];
            const int base = v0 + outer * 2048;
            #pragma unroll
            for (int i = 0; i < 8; ++i) {
                xa[i] = __builtin_nontemporal_load(&b[base + i * 256]);
                ya[i] = __builtin_nontemporal_load(&a[base + i * 256]);
                // row index is wave-uniform per chunk (256-aligned spans never
                // cross a row): force SGPR index -> scalar load, not a gather.
                int row = __builtin_amdgcn_readfirstlane((base + i * 256) >> rowShift);
                wv[i] = sw[row];
            }
            #pragma unroll
            for (int i = 0; i < 8; ++i)
                acc += wv[i] * ssq(xa[i], ya[i]);
        }

        float total = block_reduce_sum(acc, smr);
        if (tid == 0) {
            atomicAdd(&ws[region], total);
            __threadfence();                          // ws add visible before counter
            unsigned* cnt = (unsigned*)(ws + 5);
            unsigned old = atomicAdd(cnt, 1u);
            if (old == NWSE - 1) {                    // last wse block: finalize
                float s0 = atomicAdd(&ws[0], 0.f);    // coherent RMW reads
                float s1 = atomicAdd(&ws[1], 0.f);
                float s2 = atomicAdd(&ws[2], 0.f);
                float s3 = atomicAdd(&ws[3], 0.f);
                float s4 = atomicAdd(&ws[4], 0.f);
                out[1] = s0 * (1.f / (float)DC);
                out[2] = s1 * (1.f / (float)DB);
                out[3] = s2 * (1.f / (float)DB);
                out[4] = s3 * (1.f / (float)DB);
                out[5] = s4 * (1.f / (float)DB);
            }
        }
        return;
    }

    // ---- Cox branch: one block per loss (blocks 0..4) ----
    const int CH = 20;                 // 256*20 = 5120 >= 5000 buckets
    const int c  = blockIdx.x;         // 0 -> pred, 1..4 -> block_hazards
    const float* p = (c == 0) ? pred : (bh + (size_t)(c - 1) * N_SAMP);

    for (int i = tid; i < TBKT; i += 256) hist[i] = 0.f;
    __syncthreads();

    for (int j = tid; j < N_SAMP; j += 256) {
        int t = st[j];
        t = (t < 0) ? 0 : ((t >= TBKT) ? TBKT - 1 : t);
        atomicAdd(&hist[t], expf(p[j]));
    }
    __syncthreads();

    // chunk sums
    const int base = tid * CH;
    float cs = 0.f;
    for (int i = base; i < base + CH && i < TBKT; ++i) cs += hist[i];
    scan[tid] = cs;
    __syncthreads();
    // Hillis-Steele suffix scan across 256 chunks
    for (int off = 1; off < 256; off <<= 1) {
        float vv = (tid + off < 256) ? scan[tid + off] : 0.f;
        __syncthreads();
        scan[tid] += vv;
        __syncthreads();
    }
    // within-chunk suffix; hist[t] becomes S[t] = sum_{u>=t} hist_orig[u]
    float run = (tid < 255) ? scan[tid + 1] : 0.f;
    int hi = base + CH; if (hi > TBKT) hi = TBKT;
    for (int i = hi - 1; i >= base; --i) { run += hist[i]; hist[i] = run; }
    __syncthreads();

    float s = 0.f, ne = 0.f;
    for (int j = tid; j < N_SAMP; j += 256) {
        float e = (float)se[j];
        int t = st[j];
        t = (t < 0) ? 0 : ((t >= TBKT) ? TBKT - 1 : t);
        s  += sw[j] * e * (p[j] - logf(hist[t]));
        ne += e;
    }
    float S  = block_reduce_sum(s,  smr);
    float NE = block_reduce_sum(ne, smr + 4);
    if (tid == 0) {
        float loss = (NE > 0.f) ? (-S / fmaxf(NE, 1.f)) : 0.f;
        out[(c == 0) ? 0 : (5 + c)] = loss;
    }
}

extern "C" void kernel_launch(void* const* d_in, const int* in_sizes, int n_in,
                              void* d_out, int out_size, void* d_ws, size_t ws_size,
                              hipStream_t stream) {
    const float* pred = (const float*)d_in[0];
    const float* ct   = (const float*)d_in[1];
    const float* cr   = (const float*)d_in[2];
    const float* bt   = (const float*)d_in[3];
    const float* br   = (const float*)d_in[4];
    const float* bh   = (const float*)d_in[5];
    const float* sw   = (const float*)d_in[6];
    const int*   st   = (const int*)d_in[7];
    const int*   se   = (const int*)d_in[8];
    float* out = (float*)d_out;
    float* ws  = (float*)d_ws;

    hipMemsetAsync(ws, 0, 6 * sizeof(float), stream);

    fused_kernel<<<NWSE + NCOX, 256, 0, stream>>>(pred, ct, cr, bt, br, bh,
                                                  sw, st, se, ws, out);
}

// Round 7
// 67.010 us; speedup vs baseline: 3.3581x; 3.3581x over previous
//
#include <hip/hip_runtime.h>
#include <hip/hip_bf16.h>

// Problem constants (fixed by setup_inputs):
//   n = 4096, dc = 4096, nb = 4, db = 2048, T buckets = 5000
#define N_SAMP 4096
#define DC     4096
#define NB     4
#define DB     2048
#define TBKT   5000

#define CVEC (N_SAMP * DC / 4)   // 4,194,304 vec4 in common region
#define BVEC (N_SAMP * DB / 4)   // 2,097,152 vec4 per block region
#define TILE 4096                // vec4 per tile (region-pure)
#define NWSE ((CVEC + NB * BVEC) / TILE)  // 3072 wse tiles
#define NCOX 5

typedef float vf4 __attribute__((ext_vector_type(4)));  // builtin-compatible

__device__ inline float ssq(const vf4& x, const vf4& y) {
    float d0 = x.x - y.x, d1 = x.y - y.y, d2 = x.z - y.z, d3 = x.w - y.w;
    return d0 * d0 + d1 * d1 + d2 * d2 + d3 * d3;
}

__device__ inline float block_reduce_sum(float v, volatile float* sm) {
    #pragma unroll
    for (int off = 32; off > 0; off >>= 1) v += __shfl_down(v, off);
    int lane = threadIdx.x & 63;
    int wid  = threadIdx.x >> 6;
    if (lane == 0) sm[wid] = v;
    __syncthreads();
    float r = 0.f;
    if (wid == 0) {
        r = (lane < 4) ? sm[lane] : 0.f;
        r += __shfl_down(r, 2);
        r += __shfl_down(r, 1);
    }
    return r;  // valid on thread 0
}

// Fused kernel. Blocks [0,NCOX): the 5 Cox losses (dispatch first, overlap
// with the wse flood). Blocks [NCOX, NCOX+NWSE): weighted-squared-error
// streaming reduction; each block plain-stores its partial to ws[tile]
// (private slot -> no atomics, no zeroing, NO FENCES — R6's threadfence
// caused 3072 L2 writeback-invalidates and a 3x regression).
__global__ __launch_bounds__(256) void fused_kernel(
    const float* __restrict__ pred,
    const float* __restrict__ ct, const float* __restrict__ cr,
    const float* __restrict__ bt, const float* __restrict__ br,
    const float* __restrict__ bh,
    const float* __restrict__ sw, const int* __restrict__ st,
    const int* __restrict__ se,
    float* __restrict__ ws, float* __restrict__ out)
{
    __shared__ float hist[TBKT];
    __shared__ float scan[256];
    __shared__ float smr[8];
    const int tid = threadIdx.x;

    if (blockIdx.x >= NCOX) {
        const int tile = blockIdx.x - NCOX;
        const vf4* a;
        const vf4* b;
        int rowShift, vloc;
        if (tile < CVEC / TILE) {
            rowShift = 10;                   // 1024 vec4 per row
            a = (const vf4*)ct; b = (const vf4*)cr;
            vloc = tile * TILE;
        } else {
            const int q   = tile - CVEC / TILE;
            const int blk = q >> 9;          // 512 tiles per block region
            rowShift = 9;                    // 512 vec4 per row
            a = (const vf4*)bt + (size_t)blk * BVEC;
            b = (const vf4*)br + (size_t)blk * BVEC;
            vloc = (q & 511) * TILE;
        }
        const int v0 = vloc + tid;

        float acc = 0.f;
        #pragma unroll
        for (int outer = 0; outer < 2; ++outer) {
            vf4 xa[8], ya[8];
            float wv[8];
            const int base = v0 + outer * 2048;
            #pragma unroll
            for (int i = 0; i < 8; ++i) {
                xa[i] = __builtin_nontemporal_load(&b[base + i * 256]);
                ya[i] = __builtin_nontemporal_load(&a[base + i * 256]);
                // row index is wave-uniform per chunk (256-aligned spans never
                // cross a row): force SGPR index -> scalar load, not a gather.
                int row = __builtin_amdgcn_readfirstlane((base + i * 256) >> rowShift);
                wv[i] = sw[row];
            }
            #pragma unroll
            for (int i = 0; i < 8; ++i)
                acc += wv[i] * ssq(xa[i], ya[i]);
        }

        float total = block_reduce_sum(acc, smr);
        if (tid == 0) ws[tile] = total;      // private slot, plain store
        return;
    }

    // ---- Cox branch: one block per loss (blocks 0..4) ----
    const int CH = 20;                 // 256*20 = 5120 >= 5000 buckets
    const int c  = blockIdx.x;         // 0 -> pred, 1..4 -> block_hazards
    const float* p = (c == 0) ? pred : (bh + (size_t)(c - 1) * N_SAMP);

    for (int i = tid; i < TBKT; i += 256) hist[i] = 0.f;
    __syncthreads();

    for (int j = tid; j < N_SAMP; j += 256) {
        int t = st[j];
        t = (t < 0) ? 0 : ((t >= TBKT) ? TBKT - 1 : t);
        atomicAdd(&hist[t], expf(p[j]));
    }
    __syncthreads();

    // chunk sums
    const int base = tid * CH;
    float cs = 0.f;
    for (int i = base; i < base + CH && i < TBKT; ++i) cs += hist[i];
    scan[tid] = cs;
    __syncthreads();
    // Hillis-Steele suffix scan across 256 chunks
    for (int off = 1; off < 256; off <<= 1) {
        float vv = (tid + off < 256) ? scan[tid + off] : 0.f;
        __syncthreads();
        scan[tid] += vv;
        __syncthreads();
    }
    // within-chunk suffix; hist[t] becomes S[t] = sum_{u>=t} hist_orig[u]
    float run = (tid < 255) ? scan[tid + 1] : 0.f;
    int hi = base + CH; if (hi > TBKT) hi = TBKT;
    for (int i = hi - 1; i >= base; --i) { run += hist[i]; hist[i] = run; }
    __syncthreads();

    float s = 0.f, ne = 0.f;
    for (int j = tid; j < N_SAMP; j += 256) {
        float e = (float)se[j];
        int t = st[j];
        t = (t < 0) ? 0 : ((t >= TBKT) ? TBKT - 1 : t);
        s  += sw[j] * e * (p[j] - logf(hist[t]));
        ne += e;
    }
    float S  = block_reduce_sum(s,  smr);
    float NE = block_reduce_sum(ne, smr + 4);
    if (tid == 0) {
        float loss = (NE > 0.f) ? (-S / fmaxf(NE, 1.f)) : 0.f;
        out[(c == 0) ? 0 : (5 + c)] = loss;
    }
}

// Sum the 3072 per-tile partials into out[1..5]. Region boundaries (tile
// 1024/1536/2048/2560) are 256-aligned, so each unrolled step below is
// region-pure and branch-free.
__global__ __launch_bounds__(256) void finalize_kernel(
    const float* __restrict__ ws, float* __restrict__ out)
{
    __shared__ float smr[4];
    const int t = threadIdx.x;
    float a0 = ws[t] + ws[t + 256] + ws[t + 512] + ws[t + 768];
    float a1 = ws[t + 1024] + ws[t + 1280];
    float a2 = ws[t + 1536] + ws[t + 1792];
    float a3 = ws[t + 2048] + ws[t + 2304];
    float a4 = ws[t + 2560] + ws[t + 2816];

    float r0 = block_reduce_sum(a0, smr); __syncthreads();
    float r1 = block_reduce_sum(a1, smr); __syncthreads();
    float r2 = block_reduce_sum(a2, smr); __syncthreads();
    float r3 = block_reduce_sum(a3, smr); __syncthreads();
    float r4 = block_reduce_sum(a4, smr);
    if (t == 0) {
        out[1] = r0 * (1.f / (float)DC);
        out[2] = r1 * (1.f / (float)DB);
        out[3] = r2 * (1.f / (float)DB);
        out[4] = r3 * (1.f / (float)DB);
        out[5] = r4 * (1.f / (float)DB);
    }
}

extern "C" void kernel_launch(void* const* d_in, const int* in_sizes, int n_in,
                              void* d_out, int out_size, void* d_ws, size_t ws_size,
                              hipStream_t stream) {
    const float* pred = (const float*)d_in[0];
    const float* ct   = (const float*)d_in[1];
    const float* cr   = (const float*)d_in[2];
    const float* bt   = (const float*)d_in[3];
    const float* br   = (const float*)d_in[4];
    const float* bh   = (const float*)d_in[5];
    const float* sw   = (const float*)d_in[6];
    const int*   st   = (const int*)d_in[7];
    const int*   se   = (const int*)d_in[8];
    float* out = (float*)d_out;
    float* ws  = (float*)d_ws;

    fused_kernel<<<NWSE + NCOX, 256, 0, stream>>>(pred, ct, cr, bt, br, bh,
                                                  sw, st, se, ws, out);
    finalize_kernel<<<1, 256, 0, stream>>>(ws, out);
}